// Round 14
// baseline (609.223 us; speedup 1.0000x reference)
//
#include <hip/hip_runtime.h>

// ConvLSTM B=8,T=16,CIN=16,HID=64,H=W=64,K=3 'SAME' — 16-launch bf16 MFMA.
// Round-17: occupancy unlock. Audit: 72 arch VGPR + 64 AGPR = 136 unified
// regs/wave; 2 blocks x 8 waves x 136 = 2176 > 2048 per-CU regs -> since
// round-14 only ONE 8-wave block was resident per CU (LDS fit 2, registers
// did not). Fix: B-prefetch depth 3->2 (bb[4][3] -> bb[3][3], -12 regs,
// ~124 <= 128) + __launch_bounds__(512,4) to pin the allocator there.
// 16x124 = 1984 <= 2048 -> BOTH blocks resident (4 waves/SIMD): staging of
// one block overlaps K-loop of the other at identical traffic. Depth-2 B
// cover at 4 waves/SIMD ~= 464cy > 300cy L2 latency (depth-3 was
// compensating for the occupancy its own registers destroyed).
// Everything else identical to round-16 (merged prep, xsw swizzle,
// fragment-layout c, fully-unrolled tap-major K-loop).

#define B_ 8
#define T_ 16
#define CIN_ 16
#define HID_ 64
#define H_ 64
#define W_ 64
#define HW_ (H_*W_)
#define CTOT_ 80
#define XS_ROW 66                  // 64 px + 2 halo (positions per row)
#define XS_CH 128                  // 16 granules of 16B; 12 used, 4 dead
#define XS_SIZE (4*XS_ROW*XS_CH)   // 33792 hw = 67584 B
#define CSTRIDE_ (B_*HID_*HW_)     // 2097152

typedef __attribute__((ext_vector_type(8))) short short8;
typedef __attribute__((ext_vector_type(4))) float f32x4;

__device__ __forceinline__ unsigned short f2bf(float f){
    unsigned u = __float_as_uint(f);
    u = (u + 0x7FFFu + ((u >> 16) & 1u)) >> 16;   // RNE
    return (unsigned short)u;
}
__device__ __forceinline__ float sigm_(float v){ return 1.0f/(1.0f + __expf(-v)); }
__device__ __forceinline__ float tanh_(float v){ return 2.0f/(1.0f + __expf(-2.0f*v)) - 1.0f; }
// swizzled hw-index of 16B-granule `chunk` at position `pos`
__device__ __forceinline__ int xsw(int pos, int chunk){
    return (pos << 7) + (((chunk ^ pos) & 7) << 3) + ((chunk & 8) << 3);
}

// Merged prep: blocks 0..863 build Wfrag; blocks 864..2911 convert x->xbf.
// Wfrag: [tap 9][cc 3][ng 16] frags of 512 hw ([lane][j]).
// n = ng*16+(lane&15): g=n>>6, o=n&63; k-ch c = cc*32+(lane>>4)*8+j.
// Bias folded at c==80 (constant-1 A channel), center tap only.
__global__ void prep_all(const float* __restrict__ x,
                         const float* __restrict__ Wf, const float* __restrict__ Wi,
                         const float* __restrict__ Wc, const float* __restrict__ Wo,
                         const float* __restrict__ bf, const float* __restrict__ bi,
                         const float* __restrict__ bc, const float* __restrict__ bo,
                         unsigned short* __restrict__ Wfrag,
                         unsigned short* __restrict__ xbf){
    if (blockIdx.x < 864){
        int idx = blockIdx.x*256 + threadIdx.x;      // 864*256 = 221184 exact
        int j    = idx & 7;
        int lane = (idx >> 3) & 63;
        int frag = idx >> 9;
        int ng = frag & 15;
        int tc = frag >> 4;
        int cc = tc % 3, tap = tc / 3;
        int n = ng*16 + (lane & 15);
        int g = n >> 6, o = n & 63;
        int c = cc*32 + ((lane >> 4) << 3) + j;
        int ky = tap / 3, kx = tap % 3;
        float v = 0.0f;
        if (c < CTOT_){
            if (g == 0)      v = Wf[((o*CTOT_ + c)*3 + ky)*3 + kx];
            else if (g == 1) v = Wi[((o*CTOT_ + c)*3 + ky)*3 + kx];
            else if (g == 2) v = Wc[((o*CTOT_ + c)*3 + ky)*3 + kx];
            else             v = (tap == 4) ? Wo[o*CTOT_ + c] : 0.0f;
        } else if (c == CTOT_ && tap == 4){          // bias channel
            v = (g==0) ? bf[o] : (g==1) ? bi[o] : (g==2) ? bc[o] : bo[o];
        }
        Wfrag[idx] = f2bf(v);
    } else {
        // x[b][t][c][y][px] fp32 -> xbf[b][t][y][px][c16] bf16
        int idx = (blockIdx.x - 864)*256 + threadIdx.x;  // 524288 = (b,t,y,px)
        int px = idx & 63;
        int y  = (idx >> 6) & 63;
        int bt = idx >> 12;
        const float* src = x + (size_t)bt*CIN_*HW_ + y*W_ + px;
        unsigned short tmp[16];
        #pragma unroll
        for (int c = 0; c < 16; ++c) tmp[c] = f2bf(src[(size_t)c*HW_]);
        uint4* dst = (uint4*)(xbf + (size_t)idx*16);
        dst[0] = *(uint4*)(tmp);
        dst[1] = *(uint4*)(tmp + 8);
    }
}

__global__ __launch_bounds__(512, 4) void lstm_step(
    const unsigned short* __restrict__ xbf,
    const unsigned short* __restrict__ Wfrag,
    float* __restrict__ cbuf,                        // FRAGMENT layout [blk][tid][16]
    const unsigned short* __restrict__ hin,          // [b][y][px][o] bf16
    unsigned short* __restrict__ hout,
    float* __restrict__ out,                         // [h|c] std layout, t==15 only
    int t)
{
    __shared__ __align__(16) unsigned short Xs[XS_SIZE];
    const int id   = blockIdx.x;
    // XCD swizzle: id&7 -> XCD; each XCD owns a contiguous 8-row y band so
    // y+-1 halo reads stay XCD-local. 256 blocks = 32/XCD = 1/CU.
    const int xcd  = id & 7;
    const int j    = id >> 3;
    const int b    = j >> 2;
    const int y0   = xcd*8 + ((j & 3) << 1);         // row-pair start
    const int tid  = threadIdx.x;
    const int lane = tid & 63;
    const int wid  = tid >> 6;
    const int wm   = wid >> 2;                       // 0/1: which output row
    const int wn   = wid & 3;                        // N-slice
    const int l15  = lane & 15;
    const int q    = lane >> 4;

    // ---- targeted init (regions disjoint from staged commits -> one barrier)
    uint4 z4; z4.x=z4.y=z4.z=z4.w=0u;
    // P1: every pos: zero chunks 10,11 (hw 80..95), then bias 1.0 at hw 80
    if (tid < 4*XS_ROW){
        *(uint4*)(Xs + xsw(tid, 10)) = z4;
        *(uint4*)(Xs + xsw(tid, 11)) = z4;
        Xs[xsw(tid, 10)] = 0x3F80;                   // bf16 1.0 (chunk10 byte0)
    }
    // P2: halo cols px0 & px65, chunks 0..11: 8 positions x 12 = 96
    if (tid < 96){
        int pp = tid/12, ch = tid - pp*12;
        int row = pp >> 1, px = (pp & 1) ? 65 : 0;
        *(uint4*)(Xs + xsw(row*XS_ROW + px, ch)) = z4;
    }
    // P3: OOB edge rows (y0==0 -> row0, y0==62 -> row3): px1..64, chunks 0..11
    if (y0 == 0 || y0 == H_-2){
        int row = (y0 == 0) ? 0 : 3;
        for (int i = tid; i < 768; i += 512){
            int px = 1 + i/12, ch = i - (i/12)*12;
            *(uint4*)(Xs + xsw(row*XS_ROW + px, ch)) = z4;
        }
    }
    // P4: t==0: h region zero, rows 0..3, px1..64, chunks 2..9 (4/thread)
    if (t == 0){
        #pragma unroll
        for (int k = 0; k < 4; ++k){
            int i = tid + (k << 9);
            int row = i >> 9; int rem = i & 511;
            int px = 1 + (rem >> 3), ch8 = rem & 7;
            *(uint4*)(Xs + xsw(row*XS_ROW + px, 2 + ch8)) = z4;
        }
    }

    // ---- stage x: 4 rows x 64 px x 2 chunks = 512 uint4 (exactly 1/thread)
    {
        int row = tid >> 7, rem = tid & 127;
        int px = rem >> 1, ch8 = rem & 1;
        int yy = y0 + row - 1;
        if (yy >= 0 && yy < H_){
            uint4 v = *(const uint4*)(xbf + ((((size_t)(b*T_ + t)*H_ + yy)*W_ + px)*16 + ch8*8));
            *(uint4*)(Xs + xsw(row*XS_ROW + px + 1, ch8)) = v;
        }
    }
    // ---- stage h: 4 rows x 64 px x 8 chunks = 2048 uint4 (4/thread)
    if (t > 0){
        #pragma unroll
        for (int k = 0; k < 4; ++k){
            int i = tid + (k << 9);
            int row = i >> 9, rem = i & 511;
            int px = rem >> 3, ch8 = rem & 7;
            int yy = y0 + row - 1;
            if (yy >= 0 && yy < H_){
                uint4 v = *(const uint4*)(hin + ((((size_t)b*H_ + yy)*W_ + px)*HID_ + ch8*8));
                *(uint4*)(Xs + xsw(row*XS_ROW + px + 1, 2 + ch8)) = v;
            }
        }
    }
    __syncthreads();

    // ---- K-loop: 27 tc = tap*3+cc iters, FULLY unrolled, tap-major (linear
    // in Wfrag). A prefetch 2-ahead, B 2-ahead (3 slots each), c-frag loads
    // at tc==22. A granule = (cc*4+q) ^ (pos&7): conflict-free.
    f32x4 acc[4][4];
    #pragma unroll
    for (int g = 0; g < 4; ++g){
        #pragma unroll
        for (int mf = 0; mf < 4; ++mf) acc[g][mf] = (f32x4)0.0f;
    }

    const int posA = wm*XS_ROW + l15;                // + (ky*66+kx) const per tc
    const unsigned short* Bbase = Wfrag + (size_t)wn*512 + lane*8;
    float* cfr = cbuf + ((size_t)id << 13) + ((size_t)tid << 4);  // [blk][tid][16]

    short8 a[3][4], bb[3][3], bO[3];
    f32x4 cp[4];
    #pragma unroll
    for (int p = 0; p < 2; ++p){                     // preload A+B: tc=0,1
        const int tap = p/3, cc = p%3;
        const int pos = posA + (tap/3)*XS_ROW + (tap%3);
        const int ad = xsw(pos, cc*4 + q);
        #pragma unroll
        for (int mf = 0; mf < 4; ++mf)
            a[p][mf] = *(const short8*)(Xs + ad + mf*16*XS_CH);
        #pragma unroll
        for (int g = 0; g < 3; ++g)
            bb[p][g] = *(const short8*)(Bbase + p*8192 + g*2048);
    }

    #pragma unroll
    for (int tc = 0; tc < 27; ++tc){
        const int tap = tc/3;
        const int ca = tc % 3;                       // A slot (3-slot ring)
        if (tc + 2 < 27){                            // A+B prefetch, distance 2
            const int ntc = tc + 2;
            const int ntap = ntc/3, ncc = ntc%3;
            const int pos = posA + (ntap/3)*XS_ROW + (ntap%3);
            const int ad = xsw(pos, ncc*4 + q);
            #pragma unroll
            for (int mf = 0; mf < 4; ++mf)
                a[ntc%3][mf] = *(const short8*)(Xs + ad + mf*16*XS_CH);
            #pragma unroll
            for (int g = 0; g < 3; ++g)
                bb[ntc%3][g] = *(const short8*)(Bbase + ntc*8192 + g*2048);
        }
        if (tc >= 10 && tc <= 12)                    // o-gate frags for tc=12..14
            bO[tc-10] = *(const short8*)(Bbase + (tc+2)*8192 + 6144);
        if (tc == 22 && t > 0){                      // c-fragment prefetch
            #pragma unroll
            for (int mf = 0; mf < 4; ++mf)
                cp[mf] = *(const f32x4*)(cfr + mf*4);
        }
        if (tap == 4){  // o-gate: center tap only (ng=12+wn; covers bias ch)
            #pragma unroll
            for (int mf = 0; mf < 4; ++mf)
                acc[3][mf] = __builtin_amdgcn_mfma_f32_16x16x32_bf16(a[ca][mf], bO[tc-12], acc[3][mf], 0,0,0);
        }
        #pragma unroll
        for (int g = 0; g < 3; ++g){
            #pragma unroll
            for (int mf = 0; mf < 4; ++mf)
                acc[g][mf] = __builtin_amdgcn_mfma_f32_16x16x32_bf16(a[ca][mf], bb[ca][g], acc[g][mf], 0,0,0);
        }
    }

    // ---- epilogue: wave-local gates; c in fragment layout, h channel-last
    const int o = wn*16 + l15;
    const int y = y0 + wm;
    #pragma unroll
    for (int mf = 0; mf < 4; ++mf){
        f32x4 cnv;
        #pragma unroll
        for (int r = 0; r < 4; ++r){
            const int px = mf*16 + q*4 + r;
            const float fv = sigm_(acc[0][mf][r]);
            const float iv = sigm_(acc[1][mf][r]);
            const float gv = tanh_(acc[2][mf][r]);
            const float ov = sigm_(acc[3][mf][r]);
            const float cprev = t ? cp[mf][r] : 0.0f;
            const float cn = cprev*fv + iv*gv;
            const float hn = tanh_(cn)*ov;
            cnv[r] = cn;
            if (t < T_-1){
                hout[(((size_t)(b*H_ + y)*W_ + px)*HID_ + o)] = f2bf(hn);
            } else {
                const size_t oidx = ((((size_t)(b*HID_ + o))*H_ + y)*W_ + px);
                out[oidx] = hn;
                out[CSTRIDE_ + oidx] = cn;
            }
        }
        if (t < T_-1) *(f32x4*)(cfr + mf*4) = cnv;   // 16B vector c store
    }
}

extern "C" void kernel_launch(void* const* d_in, const int* in_sizes, int n_in,
                              void* d_out, int out_size, void* d_ws, size_t ws_size,
                              hipStream_t stream){
    const float* x  = (const float*)d_in[0];
    const float* Wf = (const float*)d_in[1];
    const float* bf = (const float*)d_in[2];
    const float* Wi = (const float*)d_in[3];
    const float* bi = (const float*)d_in[4];
    const float* Wc = (const float*)d_in[5];
    const float* bc = (const float*)d_in[6];
    const float* Wo = (const float*)d_in[7];
    const float* bo = (const float*)d_in[8];

    // ws: Wfrag 442368 | xbf 16777216 | cbuf_frag 8388608 | hbfA | hbfB
    unsigned short* Wfrag = (unsigned short*)d_ws;
    unsigned short* xbf   = (unsigned short*)((char*)d_ws + 442368);
    float*          cbuf  = (float*)((char*)d_ws + 442368 + 16777216);
    unsigned short* hbfA  = (unsigned short*)((char*)d_ws + 442368 + 16777216 + 8388608);
    unsigned short* hbfB  = hbfA + CSTRIDE_;

    prep_all<<<dim3(2912), dim3(256), 0, stream>>>(
        x, Wf, Wi, Wc, Wo, bf, bi, bc, bo, Wfrag, xbf);

    for (int t = 0; t < T_; ++t){
        const unsigned short* hi = (t & 1) ? hbfA : hbfB;   // t==0 never reads
        unsigned short*       ho = (t & 1) ? hbfB : hbfA;
        lstm_step<<<dim3(256), dim3(512), 0, stream>>>(
            xbf, Wfrag, cbuf, hi, ho, (float*)d_out, t);
    }
}

// Round 15
// 379.446 us; speedup vs baseline: 1.6056x; 1.6056x over previous
//
#include <hip/hip_runtime.h>

// ConvLSTM B=8,T=16,CIN=16,HID=64,H=W=64,K=3 'SAME' — 16-launch bf16 MFMA.
// Round-18 FINAL: revert to round-16 (370.0us, session best). Round-17's
// __launch_bounds__(512,4) forced 128 regs/wave against a ~190-reg live set
// -> scratch spills (WRITE 12->57.8MB/dispatch, FETCH 2->21.6MB) -> 609us.
// Confirmed: 2-blocks/CU residency is impossible with the 64-AGPR acc tile
// (16 waves x 136 regs = 2176 > 2048/CU), and the smaller tile that would
// fit (M_wave=32) measured +7-13% worse (r5/r6). Structural floor reached:
//  - tile/grid: 256blk x 512thr M=128 beats all measured alternatives
//  - schedule: fully-unrolled tap-major, A 2-ahead, B 3-ahead prefetch
//  - state: fragment-layout c (r14), bf16 h, bias+o-gate folded into MFMA
//  - LDS: XOR-swizzled conflict-free layout (r15), targeted init (r13)
//  - cross-step: stream launches beat persistent+fence 2.9x (r12: agent
//    fence = L2 wb/inv kills Wfrag residency); prep merged (r16)
// Per-step ~22us = launch/drain + staging critical path + latency-bound
// K-loop at 2 waves/SIMD; MfmaUtil ~9% vs HBM ~4%: latency floor, not a
// pipe roofline.

#define B_ 8
#define T_ 16
#define CIN_ 16
#define HID_ 64
#define H_ 64
#define W_ 64
#define HW_ (H_*W_)
#define CTOT_ 80
#define XS_ROW 66                  // 64 px + 2 halo (positions per row)
#define XS_CH 128                  // 16 granules of 16B; 12 used, 4 dead
#define XS_SIZE (4*XS_ROW*XS_CH)   // 33792 hw = 67584 B
#define CSTRIDE_ (B_*HID_*HW_)     // 2097152

typedef __attribute__((ext_vector_type(8))) short short8;
typedef __attribute__((ext_vector_type(4))) float f32x4;

__device__ __forceinline__ unsigned short f2bf(float f){
    unsigned u = __float_as_uint(f);
    u = (u + 0x7FFFu + ((u >> 16) & 1u)) >> 16;   // RNE
    return (unsigned short)u;
}
__device__ __forceinline__ float sigm_(float v){ return 1.0f/(1.0f + __expf(-v)); }
__device__ __forceinline__ float tanh_(float v){ return 2.0f/(1.0f + __expf(-2.0f*v)) - 1.0f; }
// swizzled hw-index of 16B-granule `chunk` at position `pos`
__device__ __forceinline__ int xsw(int pos, int chunk){
    return (pos << 7) + (((chunk ^ pos) & 7) << 3) + ((chunk & 8) << 3);
}

// Merged prep: blocks 0..863 build Wfrag; blocks 864..2911 convert x->xbf.
// Wfrag: [tap 9][cc 3][ng 16] frags of 512 hw ([lane][j]).
// n = ng*16+(lane&15): g=n>>6, o=n&63; k-ch c = cc*32+(lane>>4)*8+j.
// Bias folded at c==80 (constant-1 A channel), center tap only.
__global__ void prep_all(const float* __restrict__ x,
                         const float* __restrict__ Wf, const float* __restrict__ Wi,
                         const float* __restrict__ Wc, const float* __restrict__ Wo,
                         const float* __restrict__ bf, const float* __restrict__ bi,
                         const float* __restrict__ bc, const float* __restrict__ bo,
                         unsigned short* __restrict__ Wfrag,
                         unsigned short* __restrict__ xbf){
    if (blockIdx.x < 864){
        int idx = blockIdx.x*256 + threadIdx.x;      // 864*256 = 221184 exact
        int j    = idx & 7;
        int lane = (idx >> 3) & 63;
        int frag = idx >> 9;
        int ng = frag & 15;
        int tc = frag >> 4;
        int cc = tc % 3, tap = tc / 3;
        int n = ng*16 + (lane & 15);
        int g = n >> 6, o = n & 63;
        int c = cc*32 + ((lane >> 4) << 3) + j;
        int ky = tap / 3, kx = tap % 3;
        float v = 0.0f;
        if (c < CTOT_){
            if (g == 0)      v = Wf[((o*CTOT_ + c)*3 + ky)*3 + kx];
            else if (g == 1) v = Wi[((o*CTOT_ + c)*3 + ky)*3 + kx];
            else if (g == 2) v = Wc[((o*CTOT_ + c)*3 + ky)*3 + kx];
            else             v = (tap == 4) ? Wo[o*CTOT_ + c] : 0.0f;
        } else if (c == CTOT_ && tap == 4){          // bias channel
            v = (g==0) ? bf[o] : (g==1) ? bi[o] : (g==2) ? bc[o] : bo[o];
        }
        Wfrag[idx] = f2bf(v);
    } else {
        // x[b][t][c][y][px] fp32 -> xbf[b][t][y][px][c16] bf16
        int idx = (blockIdx.x - 864)*256 + threadIdx.x;  // 524288 = (b,t,y,px)
        int px = idx & 63;
        int y  = (idx >> 6) & 63;
        int bt = idx >> 12;
        const float* src = x + (size_t)bt*CIN_*HW_ + y*W_ + px;
        unsigned short tmp[16];
        #pragma unroll
        for (int c = 0; c < 16; ++c) tmp[c] = f2bf(src[(size_t)c*HW_]);
        uint4* dst = (uint4*)(xbf + (size_t)idx*16);
        dst[0] = *(uint4*)(tmp);
        dst[1] = *(uint4*)(tmp + 8);
    }
}

__global__ __launch_bounds__(512, 2) void lstm_step(
    const unsigned short* __restrict__ xbf,
    const unsigned short* __restrict__ Wfrag,
    float* __restrict__ cbuf,                        // FRAGMENT layout [blk][tid][16]
    const unsigned short* __restrict__ hin,          // [b][y][px][o] bf16
    unsigned short* __restrict__ hout,
    float* __restrict__ out,                         // [h|c] std layout, t==15 only
    int t)
{
    __shared__ __align__(16) unsigned short Xs[XS_SIZE];
    const int id   = blockIdx.x;
    // XCD swizzle: id&7 -> XCD; each XCD owns a contiguous 8-row y band so
    // y+-1 halo reads stay XCD-local. 256 blocks = 32/XCD = 1/CU.
    const int xcd  = id & 7;
    const int j    = id >> 3;
    const int b    = j >> 2;
    const int y0   = xcd*8 + ((j & 3) << 1);         // row-pair start
    const int tid  = threadIdx.x;
    const int lane = tid & 63;
    const int wid  = tid >> 6;
    const int wm   = wid >> 2;                       // 0/1: which output row
    const int wn   = wid & 3;                        // N-slice
    const int l15  = lane & 15;
    const int q    = lane >> 4;

    // ---- targeted init (regions disjoint from staged commits -> one barrier)
    uint4 z4; z4.x=z4.y=z4.z=z4.w=0u;
    // P1: every pos: zero chunks 10,11 (hw 80..95), then bias 1.0 at hw 80
    if (tid < 4*XS_ROW){
        *(uint4*)(Xs + xsw(tid, 10)) = z4;
        *(uint4*)(Xs + xsw(tid, 11)) = z4;
        Xs[xsw(tid, 10)] = 0x3F80;                   // bf16 1.0 (chunk10 byte0)
    }
    // P2: halo cols px0 & px65, chunks 0..11: 8 positions x 12 = 96
    if (tid < 96){
        int pp = tid/12, ch = tid - pp*12;
        int row = pp >> 1, px = (pp & 1) ? 65 : 0;
        *(uint4*)(Xs + xsw(row*XS_ROW + px, ch)) = z4;
    }
    // P3: OOB edge rows (y0==0 -> row0, y0==62 -> row3): px1..64, chunks 0..11
    if (y0 == 0 || y0 == H_-2){
        int row = (y0 == 0) ? 0 : 3;
        for (int i = tid; i < 768; i += 512){
            int px = 1 + i/12, ch = i - (i/12)*12;
            *(uint4*)(Xs + xsw(row*XS_ROW + px, ch)) = z4;
        }
    }
    // P4: t==0: h region zero, rows 0..3, px1..64, chunks 2..9 (4/thread)
    if (t == 0){
        #pragma unroll
        for (int k = 0; k < 4; ++k){
            int i = tid + (k << 9);
            int row = i >> 9; int rem = i & 511;
            int px = 1 + (rem >> 3), ch8 = rem & 7;
            *(uint4*)(Xs + xsw(row*XS_ROW + px, 2 + ch8)) = z4;
        }
    }

    // ---- stage x: 4 rows x 64 px x 2 chunks = 512 uint4 (exactly 1/thread)
    {
        int row = tid >> 7, rem = tid & 127;
        int px = rem >> 1, ch8 = rem & 1;
        int yy = y0 + row - 1;
        if (yy >= 0 && yy < H_){
            uint4 v = *(const uint4*)(xbf + ((((size_t)(b*T_ + t)*H_ + yy)*W_ + px)*16 + ch8*8));
            *(uint4*)(Xs + xsw(row*XS_ROW + px + 1, ch8)) = v;
        }
    }
    // ---- stage h: 4 rows x 64 px x 8 chunks = 2048 uint4 (4/thread)
    if (t > 0){
        #pragma unroll
        for (int k = 0; k < 4; ++k){
            int i = tid + (k << 9);
            int row = i >> 9, rem = i & 511;
            int px = rem >> 3, ch8 = rem & 7;
            int yy = y0 + row - 1;
            if (yy >= 0 && yy < H_){
                uint4 v = *(const uint4*)(hin + ((((size_t)b*H_ + yy)*W_ + px)*HID_ + ch8*8));
                *(uint4*)(Xs + xsw(row*XS_ROW + px + 1, 2 + ch8)) = v;
            }
        }
    }
    __syncthreads();

    // ---- K-loop: 27 tc = tap*3+cc iters, FULLY unrolled, tap-major (linear
    // in Wfrag). A prefetch 2-ahead, B 3-ahead, c-frag loads at tc==22.
    // A granule = (cc*4+q) ^ (pos&7): conflict-free (8 lanes/bank-cluster).
    f32x4 acc[4][4];
    #pragma unroll
    for (int g = 0; g < 4; ++g){
        #pragma unroll
        for (int mf = 0; mf < 4; ++mf) acc[g][mf] = (f32x4)0.0f;
    }

    const int posA = wm*XS_ROW + l15;                // + (ky*66+kx) const per tc
    const unsigned short* Bbase = Wfrag + (size_t)wn*512 + lane*8;
    float* cfr = cbuf + ((size_t)id << 13) + ((size_t)tid << 4);  // [blk][tid][16]

    short8 a[3][4], bb[4][3], bO[3];
    f32x4 cp[4];
    #pragma unroll
    for (int p = 0; p < 2; ++p){                     // preload A: tc=0,1
        const int tap = p/3, cc = p%3;
        const int pos = posA + (tap/3)*XS_ROW + (tap%3);
        const int ad = xsw(pos, cc*4 + q);
        #pragma unroll
        for (int mf = 0; mf < 4; ++mf)
            a[p][mf] = *(const short8*)(Xs + ad + mf*16*XS_CH);
    }
    #pragma unroll
    for (int p = 0; p < 3; ++p){                     // preload B: tc=0,1,2
        #pragma unroll
        for (int g = 0; g < 3; ++g)
            bb[p][g] = *(const short8*)(Bbase + p*8192 + g*2048);
    }

    #pragma unroll
    for (int tc = 0; tc < 27; ++tc){
        const int tap = tc/3;
        const int ca = tc % 3;                       // A slot
        const int cb = tc % 4;                       // B slot
        if (tc + 2 < 27){                            // A prefetch, distance 2
            const int ntc = tc + 2;
            const int ntap = ntc/3, ncc = ntc%3;
            const int pos = posA + (ntap/3)*XS_ROW + (ntap%3);
            const int ad = xsw(pos, ncc*4 + q);
            #pragma unroll
            for (int mf = 0; mf < 4; ++mf)
                a[ntc%3][mf] = *(const short8*)(Xs + ad + mf*16*XS_CH);
        }
        if (tc + 3 < 27){                            // B prefetch, distance 3
            const int ntc = tc + 3;
            #pragma unroll
            for (int g = 0; g < 3; ++g)
                bb[ntc%4][g] = *(const short8*)(Bbase + ntc*8192 + g*2048);
        }
        if (tc >= 9 && tc <= 11)                     // o-gate frags for tc=12..14
            bO[tc-9] = *(const short8*)(Bbase + (tc+3)*8192 + 6144);
        if (tc == 22 && t > 0){                      // c-fragment prefetch
            #pragma unroll
            for (int mf = 0; mf < 4; ++mf)
                cp[mf] = *(const f32x4*)(cfr + mf*4);
        }
        if (tap == 4){  // o-gate: center tap only (ng=12+wn; covers bias ch)
            #pragma unroll
            for (int mf = 0; mf < 4; ++mf)
                acc[3][mf] = __builtin_amdgcn_mfma_f32_16x16x32_bf16(a[ca][mf], bO[tc-12], acc[3][mf], 0,0,0);
        }
        #pragma unroll
        for (int g = 0; g < 3; ++g){
            #pragma unroll
            for (int mf = 0; mf < 4; ++mf)
                acc[g][mf] = __builtin_amdgcn_mfma_f32_16x16x32_bf16(a[ca][mf], bb[cb][g], acc[g][mf], 0,0,0);
        }
    }

    // ---- epilogue: wave-local gates; c in fragment layout, h channel-last
    const int o = wn*16 + l15;
    const int y = y0 + wm;
    #pragma unroll
    for (int mf = 0; mf < 4; ++mf){
        f32x4 cnv;
        #pragma unroll
        for (int r = 0; r < 4; ++r){
            const int px = mf*16 + q*4 + r;
            const float fv = sigm_(acc[0][mf][r]);
            const float iv = sigm_(acc[1][mf][r]);
            const float gv = tanh_(acc[2][mf][r]);
            const float ov = sigm_(acc[3][mf][r]);
            const float cprev = t ? cp[mf][r] : 0.0f;
            const float cn = cprev*fv + iv*gv;
            const float hn = tanh_(cn)*ov;
            cnv[r] = cn;
            if (t < T_-1){
                hout[(((size_t)(b*H_ + y)*W_ + px)*HID_ + o)] = f2bf(hn);
            } else {
                const size_t oidx = ((((size_t)(b*HID_ + o))*H_ + y)*W_ + px);
                out[oidx] = hn;
                out[CSTRIDE_ + oidx] = cn;
            }
        }
        if (t < T_-1) *(f32x4*)(cfr + mf*4) = cnv;   // 16B vector c store
    }
}

extern "C" void kernel_launch(void* const* d_in, const int* in_sizes, int n_in,
                              void* d_out, int out_size, void* d_ws, size_t ws_size,
                              hipStream_t stream){
    const float* x  = (const float*)d_in[0];
    const float* Wf = (const float*)d_in[1];
    const float* bf = (const float*)d_in[2];
    const float* Wi = (const float*)d_in[3];
    const float* bi = (const float*)d_in[4];
    const float* Wc = (const float*)d_in[5];
    const float* bc = (const float*)d_in[6];
    const float* Wo = (const float*)d_in[7];
    const float* bo = (const float*)d_in[8];

    // ws: Wfrag 442368 | xbf 16777216 | cbuf_frag 8388608 | hbfA | hbfB
    unsigned short* Wfrag = (unsigned short*)d_ws;
    unsigned short* xbf   = (unsigned short*)((char*)d_ws + 442368);
    float*          cbuf  = (float*)((char*)d_ws + 442368 + 16777216);
    unsigned short* hbfA  = (unsigned short*)((char*)d_ws + 442368 + 16777216 + 8388608);
    unsigned short* hbfB  = hbfA + CSTRIDE_;

    prep_all<<<dim3(2912), dim3(256), 0, stream>>>(
        x, Wf, Wi, Wc, Wo, bf, bi, bc, bo, Wfrag, xbf);

    for (int t = 0; t < T_; ++t){
        const unsigned short* hi = (t & 1) ? hbfA : hbfB;   // t==0 never reads
        unsigned short*       ho = (t & 1) ? hbfB : hbfA;
        lstm_step<<<dim3(256), dim3(512), 0, stream>>>(
            xbf, Wfrag, cbuf, hi, ho, (float*)d_out, t);
    }
}